// Round 9
// baseline (220.806 us; speedup 1.0000x reference)
//
#include <hip/hip_runtime.h>
#include <cstdint>

// Linear-chain CRF log-partition, B=64, T=4096, S=64.
// R14: fix the single-launch trigger ordering bug.
//  - R12/R13 post-mortem: "no-init mod-15 counter" was WRONG — with garbage
//    start v, old%15==14 can fire on an EARLY arrival (e.g. v=12 -> 3rd),
//    finale reads not-yet-written wbuf/zfirst/partial. Timed graph hides it
//    (stale lines = previous replay's identical values -> absmax 0.0);
//    launch_once after ws re-poison diverges (the tripwire). Also explains
//    R12's NaN (log2 of poison). Fix: hipMemsetAsync(cnt,0) in-graph before
//    the kernel (memset nodes are capture-legal; harness reset() uses them)
//    + trigger strictly on old == BPB_-1 (true 15th arrival).
//  - Keep R13 release/acquire fencing for cross-XCD visibility.
//  - Keep (256,2): 128-VGPR cap ((256,4) -> 64-cap spilled 23MB in R11).

#define B_    64
#define T_    4096
#define S_    64
#define L_    9
#define NC_   455                 // 455*9 = 4095 = T_-1
#define BPB_  15                  // blocks per batch (32 chains per block)
#define LOG2E 1.44269504088896340736f

typedef float  f32x4  __attribute__((ext_vector_type(4)));
typedef __bf16 bf16x8 __attribute__((ext_vector_type(8)));
union U4B { uint4 u; bf16x8 b; };

__global__ __launch_bounds__(256, 2) void crf_fused(
    const float* __restrict__ scores,      // (B,T,S)
    const float* __restrict__ transition,  // (S,S) [from,to]
    const float* __restrict__ source, const float* __restrict__ sink,
    float* __restrict__ zfirst,            // (B*BPB, 64) raw zhat of chain 32j
    float* __restrict__ wbuf,              // (B*BPB, 64) y_last*em_end
    float* __restrict__ Ltlast,            // (B*BPB)     Ltz of chain 32j+31
    float* __restrict__ partial,           // (B*BPB)     per-block term sum
    unsigned* __restrict__ cnt,            // (B_) arrival counters (memset 0)
    float* __restrict__ out)               // (B_)
{
    __shared__ float tb[4][16][68];        // per-wave transpose slice
    __shared__ float ys[32][64];           // y'   (block chains 0..31)
    __shared__ float zs[32][64];           // zhat (block chains 0..31)
    __shared__ float Ltz[32];
    __shared__ float part[16];
    __shared__ unsigned trig;

    const int j  = blockIdx.x % BPB_;      // block within batch
    const int b  = blockIdx.x / BPB_;
    const int wv = threadIdx.x >> 6;       // 0,1 fwd; 2,3 bwd
    const bool bwd = wv >= 2;
    const int wg = 2 * j + (wv & 1);       // chunk-group handled by this wave
    const int lane = threadIdx.x & 63, g = lane >> 4, l = lane & 15;

    // A-side emission pointer: chain = local row l, states 8g.. contiguous
    int cl = 16 * wg + l; if (cl > NC_ - 1) cl = NC_ - 1;
    const float* ap = scores + ((size_t)b * T_ + L_ * cl + (bwd ? L_ : 0)) * S_ + 8 * g;

    f32x4 acc[4];
    f32x4 ring[3][4];                      // depth-3 prefetch ring (48 VGPRs)
    int   Lt[4] = {0, 0, 0, 0};

    auto ldq = [&](int idx, f32x4* q) {
        const float* p = ap + (ptrdiff_t)idx * S_;
        q[0] = *(const f32x4*)p;        q[1] = *(const f32x4*)(p + 4);
        q[2] = *(const f32x4*)(p + 32); q[3] = *(const f32x4*)(p + 36);
    };

    // ---- E fragments: fwd B[k][n]=exp(T[k][n]); bwd =exp(T[n][k])
    bf16x8 BE[2][4];
    #pragma unroll
    for (int kb = 0; kb < 2; ++kb)
    #pragma unroll
    for (int nt = 0; nt < 4; ++nt) {
        bf16x8 t;
        #pragma unroll
        for (int dd = 0; dd < 4; ++dd) {
            int k0 = 32 * kb + 8 * g + 2 * dd, n = 16 * nt + l;
            float e0, e1;
            if (!bwd) { e0 = transition[k0 * 64 + n]; e1 = transition[(k0 + 1) * 64 + n]; }
            else      { e0 = transition[n * 64 + k0]; e1 = transition[n * 64 + k0 + 1]; }
            t[2 * dd]     = (__bf16)exp2f(e0 * LOG2E);
            t[2 * dd + 1] = (__bf16)exp2f(e1 * LOG2E);
        }
        BE[kb][nt] = t;
    }

    auto mfma8 = [&](bf16x8 A0, bf16x8 A1) {
        #pragma unroll
        for (int nt = 0; nt < 4; ++nt) {
            f32x4 z4 = {0.f, 0.f, 0.f, 0.f};
            z4      = __builtin_amdgcn_mfma_f32_16x16x32_bf16(A0, BE[0][nt], z4, 0, 0, 0);
            acc[nt] = __builtin_amdgcn_mfma_f32_16x16x32_bf16(A1, BE[1][nt], z4, 0, 0, 0);
        }
    };
    auto renorm = [&]() {
        #pragma unroll
        for (int r = 0; r < 4; ++r) {
            float m = fmaxf(fmaxf(acc[0][r], acc[1][r]), fmaxf(acc[2][r], acc[3][r]));
            m = fmaxf(m, __shfl_xor(m, 1, 64));
            m = fmaxf(m, __shfl_xor(m, 2, 64));
            m = fmaxf(m, __shfl_xor(m, 4, 64));
            m = fmaxf(m, __shfl_xor(m, 8, 64));
            int ex = (int)(__float_as_uint(m) >> 23) - 127;
            float sc = __uint_as_float((unsigned)(127 - ex) << 23);   // exact 2^-ex
            Lt[r] += ex;
            #pragma unroll
            for (int nt = 0; nt < 4; ++nt) acc[nt][r] *= sc;
        }
    };
    // transpose acc (C: chain 4g+r, state 16nt+l) -> per-lane A rows, * em, pack
    auto xposeA = [&](const f32x4& c0, const f32x4& c1,
                      const f32x4& c2, const f32x4& c3, bf16x8& A0, bf16x8& A1) {
        #pragma unroll
        for (int nt = 0; nt < 4; ++nt)
            #pragma unroll
            for (int r = 0; r < 4; ++r)
                tb[wv][4 * g + r][16 * nt + l] = acc[nt][r];
        __builtin_amdgcn_s_waitcnt(0xC07F);        // lgkmcnt(0) only, vmcnt open
        __builtin_amdgcn_wave_barrier();
        const float* rowp = &tb[wv][l][8 * g];
        f32x4 x0 = *(const f32x4*)rowp;
        f32x4 x1 = *(const f32x4*)(rowp + 4);
        f32x4 x2 = *(const f32x4*)(rowp + 32);
        f32x4 x3 = *(const f32x4*)(rowp + 36);
        #pragma unroll
        for (int d = 0; d < 4; ++d) {
            A0[d]     = (__bf16)(x0[d] * exp2f(c0[d] * LOG2E));
            A0[d + 4] = (__bf16)(x1[d] * exp2f(c1[d] * LOG2E));
            A1[d]     = (__bf16)(x2[d] * exp2f(c2[d] * LOG2E));
            A1[d + 4] = (__bf16)(x3[d] * exp2f(c3[d] * LOG2E));
        }
    };

    if (!bwd) {
        // y'_c = 1^T E d1 E ... d8 E  (em rows t0+1..t0+8; d9 in recombination)
        ldq(1, ring[0]); ldq(2, ring[1]); ldq(3, ring[2]);
        { U4B t; t.u = make_uint4(0x3F803F80u, 0x3F803F80u, 0x3F803F80u, 0x3F803F80u);
          mfma8(t.b, t.b); }                       // tt=0: A = ones
        #pragma unroll
        for (int tt = 1; tt < L_; ++tt) {
            f32x4* q = ring[(tt - 1) % 3];
            f32x4 c0 = q[0], c1 = q[1], c2 = q[2], c3 = q[3];
            if (tt + 3 <= L_ - 1) ldq(tt + 3, ring[(tt - 1) % 3]);
            bf16x8 A0, A1;
            xposeA(c0, c1, c2, c3, A0, A1);
            mfma8(A0, A1);
            if ((tt & 3) == 3) renorm();
        }
        #pragma unroll
        for (int nt = 0; nt < 4; ++nt)
            #pragma unroll
            for (int r = 0; r < 4; ++r)
                ys[16 * (wv & 1) + 4 * g + r][16 * nt + l] = acc[nt][r];
    } else {
        // zhat_c = E d1 E ... E d9 * 1, rows consumed descending (9..1)
        ldq(0, ring[0]); ldq(-1, ring[1]); ldq(-2, ring[2]);
        {   // i=0: A = em(row t0+9) (z = ones)
            f32x4* q = ring[0];
            bf16x8 A0, A1;
            #pragma unroll
            for (int d = 0; d < 4; ++d) {
                A0[d]     = (__bf16)exp2f(q[0][d] * LOG2E);
                A0[d + 4] = (__bf16)exp2f(q[1][d] * LOG2E);
                A1[d]     = (__bf16)exp2f(q[2][d] * LOG2E);
                A1[d + 4] = (__bf16)exp2f(q[3][d] * LOG2E);
            }
            mfma8(A0, A1);
            ldq(-3, ring[0]);
        }
        #pragma unroll
        for (int i = 1; i < L_; ++i) {
            f32x4* q = ring[i % 3];
            f32x4 c0 = q[0], c1 = q[1], c2 = q[2], c3 = q[3];
            if (i + 3 <= L_ - 1) ldq(-(i + 3), ring[i % 3]);
            bf16x8 A0, A1;
            xposeA(c0, c1, c2, c3, A0, A1);
            mfma8(A0, A1);
            if ((i & 3) == 3) renorm();
        }
        #pragma unroll
        for (int nt = 0; nt < 4; ++nt)
            #pragma unroll
            for (int r = 0; r < 4; ++r)
                zs[16 * (wv & 1) + 4 * g + r][16 * nt + l] = acc[nt][r];
        if (l == 0) {
            #pragma unroll
            for (int r = 0; r < 4; ++r)
                Ltz[16 * (wv & 1) + 4 * g + r] = (float)Lt[r];
        }
    }
    __syncthreads();

    // ---- export zfirst (raw zhat of block chain 0)
    if (wv == 0) zfirst[((size_t)(b * BPB_ + j)) * 64 + lane] = zs[0][lane];

    // ---- in-block rank-1 recombination: quad (wv,q) handles chains
    // m = 8*wv + 2*q + {0,1}; lane l covers states l, l+16, l+32, l+48.
    const int q = g;
    float myterm = 0.f;
    #pragma unroll
    for (int h = 0; h < 2; ++h) {
        const int m = 8 * wv + 2 * q + h;
        const int c = 32 * j + m;
        const int cc = c < NC_ ? c : NC_ - 1;
        const float* er = scores + ((size_t)b * T_ + (size_t)L_ * (cc + 1)) * S_;
        float ye[4], pp = 0.f, qs = 0.f;
        #pragma unroll
        for (int k = 0; k < 4; ++k) {
            ye[k] = ys[m][16 * k + l] * exp2f(er[16 * k + l] * LOG2E);
            float zz = (c == NC_ - 1) ? exp2f(sink[16 * k + l] * LOG2E)
                                      : zs[(m + 1) & 31][16 * k + l];
            pp += ye[k] * zz;
            qs += ye[k];
        }
        #pragma unroll
        for (int mm = 1; mm <= 8; mm <<= 1) {
            pp += __shfl_xor(pp, mm, 64);
            qs += __shfl_xor(qs, mm, 64);
        }
        if (m == 31) {
            if (c < NC_ - 1) {   // real boundary -> closed by trigger wave
                #pragma unroll
                for (int k = 0; k < 4; ++k)
                    wbuf[((size_t)(b * BPB_ + j)) * 64 + 16 * k + l] = ye[k];
                if (l == 0) Ltlast[b * BPB_ + j] = Ltz[31];
            }
        } else if (c < NC_ && l == 0) {
            myterm += log2f(pp) - log2f(qs) + Ltz[m];
        }
    }
    // a0 . zhat_0 term (first block of batch only)
    if (j == 0 && wv == 0 && q == 0) {
        float s0 = 0.f;
        #pragma unroll
        for (int k = 0; k < 4; ++k) {
            float a0 = exp2f((source[16 * k + l]
                              + scores[(size_t)b * T_ * S_ + 16 * k + l]) * LOG2E);
            s0 += a0 * zs[0][16 * k + l];
        }
        #pragma unroll
        for (int mm = 1; mm <= 8; mm <<= 1) s0 += __shfl_xor(s0, mm, 64);
        if (l == 0) myterm += log2f(s0);
    }
    if (l == 0) part[4 * wv + q] = myterm;
    __syncthreads();
    if (threadIdx.x == 0) {
        float s = 0.f;
        #pragma unroll
        for (int i = 0; i < 16; ++i) s += part[i];
        partial[b * BPB_ + j] = s;
    }

    // ---- arrival + last-block-per-batch finale (single-launch design) ----
    __threadfence();                       // RELEASE: writes visible at LLC
    __syncthreads();                       // every storer has fenced
    if (threadIdx.x == 0) {
        unsigned old = __hip_atomic_fetch_add(&cnt[b], 1u, __ATOMIC_ACQ_REL,
                                              __HIP_MEMORY_SCOPE_AGENT);
        trig = (old == (unsigned)(BPB_ - 1)) ? 1u : 0u;   // true 15th arrival
    }
    __syncthreads();
    if (trig && wv == 0) {
        __threadfence();                   // ACQUIRE: invalidate stale local L2
        // wave 0 closes the 14 boundary terms + sums the 15 partials.
        float acc2 = 0.f;
        for (int jj = 0; jj < BPB_ - 1; ++jj) {
            float w  = __hip_atomic_load(&wbuf  [((size_t)(b * BPB_ + jj)) * 64 + lane],
                                         __ATOMIC_RELAXED, __HIP_MEMORY_SCOPE_AGENT);
            float zf = __hip_atomic_load(&zfirst[((size_t)(b * BPB_ + jj + 1)) * 64 + lane],
                                         __ATOMIC_RELAXED, __HIP_MEMORY_SCOPE_AGENT);
            float pp = w * zf, qs = w;
            #pragma unroll
            for (int mm = 1; mm <= 32; mm <<= 1) {
                pp += __shfl_xor(pp, mm, 64);
                qs += __shfl_xor(qs, mm, 64);
            }
            if (lane == 0) {
                float lt = __hip_atomic_load(&Ltlast[b * BPB_ + jj],
                                             __ATOMIC_RELAXED, __HIP_MEMORY_SCOPE_AGENT);
                acc2 += log2f(pp) - log2f(qs) + lt;
            }
        }
        if (lane == 0) {
            float s = acc2;
            for (int jj = 0; jj < BPB_; ++jj)
                s += __hip_atomic_load(&partial[b * BPB_ + jj],
                                       __ATOMIC_RELAXED, __HIP_MEMORY_SCOPE_AGENT);
            out[b] = 0.6931471805599453f * s + 4.158883083359672f;  // ln2*log2Z+ln64
        }
    }
}

extern "C" void kernel_launch(void* const* d_in, const int* in_sizes, int n_in,
                              void* d_out, int out_size, void* d_ws, size_t ws_size,
                              hipStream_t stream) {
    (void)in_sizes; (void)n_in; (void)out_size; (void)ws_size;
    const float* scores     = (const float*)d_in[0];
    const float* transition = (const float*)d_in[1];
    const float* source     = (const float*)d_in[2];
    const float* sink       = (const float*)d_in[3];
    float* out = (float*)d_out;

    float*    zfirst  = (float*)d_ws;                     // 64*15*64 f32 = 245KB
    float*    wbuf    = zfirst + (size_t)B_ * BPB_ * 64;  // 245KB
    float*    Ltlast  = wbuf   + (size_t)B_ * BPB_ * 64;  // 3.8KB
    float*    partial = Ltlast + (size_t)B_ * BPB_;       // 3.8KB
    unsigned* cnt     = (unsigned*)(partial + (size_t)B_ * BPB_); // 256B

    hipMemsetAsync(cnt, 0, B_ * sizeof(unsigned), stream);  // graph-capturable
    hipLaunchKernelGGL(crf_fused, dim3(B_ * BPB_), dim3(256), 0, stream,
                       scores, transition, source, sink,
                       zfirst, wbuf, Ltlast, partial, cnt, out);
}